// Round 10
// baseline (315.080 us; speedup 1.0000x reference)
//
#include <hip/hip_runtime.h>
#include <hip/hip_bf16.h>
#include <math.h>

#define NN 8192
#define HD 128
#define NB 2
#define EPSF 1e-6f
#define BM 32
#define BKE 256               // bf16 K elements per step (tile = 32x256x2B = 16 KB)
#define NSTEP (NN / BKE)      // 32

typedef __attribute__((ext_vector_type(8))) __bf16 bf16x8;
typedef __attribute__((ext_vector_type(4))) __bf16 bf16x4;
typedef __attribute__((ext_vector_type(4))) float f32x4;

// ---- Kernel 1: norm = rsqrt(sum|adj_row|+eps)  AND  adjh = bf16(adj) --------
// Pure streaming: reads 537 MB fp32, writes 268 MB bf16. Rebalances the adj
// bytes out of the latency-bound gemm into the ~6 TB/s streaming regime
// (total HBM bytes unchanged). Fully coalesced: float4 loads, bf16x4 stores.
__global__ __launch_bounds__(256) void k_degcast(const float* __restrict__ adj,
                                                 float* __restrict__ norm,
                                                 __hip_bfloat16* __restrict__ adjh) {
    const int row  = blockIdx.x * 4 + (threadIdx.x >> 6);
    const int lane = threadIdx.x & 63;
    const float4* p = (const float4*)(adj + (size_t)row * NN);
    bf16x4* q = (bf16x4*)(adjh + (size_t)row * NN);
    float s = 0.f;
#pragma unroll
    for (int i = 0; i < 16; ++i) {
        float4 a = p[i * 128 + lane];
        float4 b = p[i * 128 + 64 + lane];
        s += fabsf(a.x) + fabsf(a.y) + fabsf(a.z) + fabsf(a.w)
           + fabsf(b.x) + fabsf(b.y) + fabsf(b.z) + fabsf(b.w);
        bf16x4 ha, hb;
        ha[0] = (__bf16)a.x; ha[1] = (__bf16)a.y; ha[2] = (__bf16)a.z; ha[3] = (__bf16)a.w;
        hb[0] = (__bf16)b.x; hb[1] = (__bf16)b.y; hb[2] = (__bf16)b.z; hb[3] = (__bf16)b.w;
        q[i * 128 + lane]      = ha;
        q[i * 128 + 64 + lane] = hb;
    }
#pragma unroll
    for (int off = 32; off > 0; off >>= 1) s += __shfl_down(s, off);
    if (lane == 0) norm[row] = rsqrtf(s + EPSF);
}

// ------- Kernel 2: snT[b][h][n] = bf16( (x@W)[b][n][h] * norm[b][n] ) --------
__global__ __launch_bounds__(256) void k_support(const float* __restrict__ x,
                                                 const float* __restrict__ W,
                                                 const float* __restrict__ norm,
                                                 __hip_bfloat16* __restrict__ snT) {
    const int b  = blockIdx.x >> 9;
    const int n0 = (blockIdx.x & 511) * 16;
    __shared__ float xs[16][132];
    const int t = threadIdx.x;
    {
        const int r = t >> 4, c0 = (t & 15) * 8;
        const float* src = x + ((size_t)(b * NN + n0 + r)) * HD + c0;
        *(float4*)&xs[r][c0]     = *(const float4*)src;
        *(float4*)&xs[r][c0 + 4] = *(const float4*)(src + 4);
    }
    __syncthreads();
    const int nl = t & 15;
    const int h0 = (t >> 4) * 8;
    float s[8] = {0.f,0.f,0.f,0.f,0.f,0.f,0.f,0.f};
#pragma unroll 4
    for (int k = 0; k < HD; ++k) {
        const float xv = xs[nl][k];
        const float* wr = W + k * HD + h0;
        float4 wa = *(const float4*)wr;
        float4 wb = *(const float4*)(wr + 4);
        s[0] += xv * wa.x; s[1] += xv * wa.y; s[2] += xv * wa.z; s[3] += xv * wa.w;
        s[4] += xv * wb.x; s[5] += xv * wb.y; s[6] += xv * wb.z; s[7] += xv * wb.w;
    }
    const float nv = norm[b * NN + n0 + nl];
#pragma unroll
    for (int hb = 0; hb < 8; ++hb)
        snT[((size_t)b * HD + h0 + hb) * NN + n0 + nl] = __float2bfloat16(s[hb] * nv);
}

// async global->LDS, 16 B per lane (dest = wave-uniform base + lane*16)
__device__ __forceinline__ void gload_lds16(const void* g, void* l) {
    __builtin_amdgcn_global_load_lds(
        (const __attribute__((address_space(1))) void*)g,
        (__attribute__((address_space(3))) void*)l, 16, 0, 0);
}

// ---- Kernel 3: out = elu( norm_m * (adjh[b] @ snT[b]^T) + bias ) ------------
// A is now bf16 (pre-cast by k_degcast): BK=256 keeps the 16 KB tile but
// halves the step count, and LDS feeds MFMA A-fragments directly (one
// ds_read_b128 each, zero cvt VALU). 512 threads = 8 waves splitting h
// (16 each): 16 waves/CU at 2 blocks/CU (LDS 64 KB, VGPR capped 128).
// R9-verified counted-vmcnt pipeline: WAITN (before BAR) guarantees this
// wave's stage(k) retired, so after BAR all waves' tile-k parts are in LDS;
// 4 buffers give 2-barrier overwrite distance. Per iter ops: B=8, stage=2.
// At WAITN outstanding <= [st(k)2, st(k+1)2, B(k)8] -> WAITN(10) retires
// st(k); tail peels use 10 and 8. Both-sides XOR swizzle unchanged
// (16B-granule ^ row&7 on global source and LDS read; 32 granules/row).
__global__ __launch_bounds__(512, 4) void k_gemm10(const __hip_bfloat16* __restrict__ adjh,
                                                   const __hip_bfloat16* __restrict__ snT,
                                                   const float* __restrict__ norm,
                                                   const float* __restrict__ bias,
                                                   float* __restrict__ out) {
    const int b    = blockIdx.y;
    const int swz  = (blockIdx.x & 7) * 32 + (blockIdx.x >> 3);   // XCD-bijective
    const int m0   = swz * BM;
    const int w    = threadIdx.x >> 6;     // 0..7, h-slice owner (h0 = w*16)
    const int lane = threadIdx.x & 63;
    const int fr   = lane & 15;
    const int g    = lane >> 4;
    const int xr   = fr & 7;

    const __hip_bfloat16* adjB = adjh + (size_t)b * NN * NN;
    const __hip_bfloat16* snB  = snT  + (size_t)b * HD * NN;

    __shared__ __align__(16) char Abuf[4][BM * BKE * 2];   // 4 x 16 KB

    // staging: wave w, call c covers 16B-granules fg = (w*2+c)*64 + lane;
    // row = fg>>5 (32 granules of 16 B per 512 B row), slot = (fg&31)^(row&7)
    const __hip_bfloat16* sp[2];
#pragma unroll
    for (int c = 0; c < 2; ++c) {
        const int fg   = (w * 2 + c) * 64 + lane;
        const int row  = fg >> 5;
        const int slot = (fg & 31) ^ (row & 7);
        sp[c] = adjB + (size_t)(m0 + row) * NN + slot * 8;
    }

    const __hip_bfloat16* bp = snB + (size_t)(w * 16 + fr) * NN + g * 8;

    f32x4 acc[2] = {};        // [m-tile]
    bf16x8 Bf[8];

#define STAGE(idx) do {                                                       \
        char* nb_ = Abuf[(idx) & 3];                                          \
        _Pragma("unroll")                                                     \
        for (int c = 0; c < 2; ++c)                                           \
            gload_lds16(sp[c] + (size_t)(idx) * BKE, &nb_[(w * 2 + c) * 1024]); \
    } while (0)
#define LOADB(idx) do {                                                       \
        _Pragma("unroll")                                                     \
        for (int ks = 0; ks < 8; ++ks)                                        \
            Bf[ks] = *(const bf16x8*)(bp + (size_t)(idx) * BKE + ks * 32);    \
    } while (0)
#define WAITN(n) asm volatile("s_waitcnt vmcnt(" #n ")" ::: "memory")
#define BAR() do { __builtin_amdgcn_s_barrier();                              \
                   __builtin_amdgcn_sched_barrier(0); } while (0)
#define COMPUTE(kidx) do {                                                    \
        const char* lb_ = Abuf[(kidx) & 3];                                   \
        _Pragma("unroll")                                                     \
        for (int mt = 0; mt < 2; ++mt) {                                      \
            const char* rbase_ = lb_ + (mt * 16 + fr) * 512;                  \
            _Pragma("unroll")                                                 \
            for (int ks = 0; ks < 8; ++ks) {                                  \
                bf16x8 af_ = *(const bf16x8*)(rbase_ + (((ks * 4 + g) ^ xr) << 4)); \
                acc[mt] = __builtin_amdgcn_mfma_f32_16x16x32_bf16(af_, Bf[ks], acc[mt], 0, 0, 0); \
            }                                                                 \
        }                                                                     \
    } while (0)

    // ---- prologue ----
    STAGE(0);
    STAGE(1);

    // ---- main loop ----
#pragma unroll 1
    for (int k = 0; k < NSTEP - 2; ++k) {
        LOADB(k);
        WAITN(10);          // st(k) retired; st(k+1), B(k) stay in flight
        BAR();
        STAGE(k + 2);
        __builtin_amdgcn_sched_barrier(0);
        COMPUTE(k);
    }

    // ---- tail (no staging) ----
    LOADB(NSTEP - 2);
    WAITN(10); BAR();
    COMPUTE(NSTEP - 2);

    LOADB(NSTEP - 1);
    WAITN(8);  BAR();
    COMPUTE(NSTEP - 1);

#undef STAGE
#undef LOADB
#undef WAITN
#undef BAR
#undef COMPUTE

    // ---- fused epilogue: *norm_m + bias, elu ----
    const float* normB = norm + b * NN + m0;
    float* outB = out + ((size_t)b * NN + m0) * HD;
    const int h  = w * 16 + fr;
    const float bv = bias[h];
#pragma unroll
    for (int mt = 0; mt < 2; ++mt)
#pragma unroll
        for (int j = 0; j < 4; ++j) {
            const int r = mt * 16 + g * 4 + j;
            float v = acc[mt][j] * normB[r] + bv;
            v = v > 0.f ? v : expm1f(v);
            outB[(size_t)r * HD + h] = v;
        }
}

extern "C" void kernel_launch(void* const* d_in, const int* in_sizes, int n_in,
                              void* d_out, int out_size, void* d_ws, size_t ws_size,
                              hipStream_t stream) {
    (void)in_sizes; (void)n_in; (void)out_size; (void)ws_size;
    const float* x    = (const float*)d_in[0];
    const float* adj  = (const float*)d_in[1];
    const float* W    = (const float*)d_in[2];
    const float* bias = (const float*)d_in[3];
    float* out = (float*)d_out;

    float* norm = (float*)d_ws;                                     // 64 KB
    __hip_bfloat16* snT  = (__hip_bfloat16*)((char*)d_ws + 65536);  // 4 MB
    __hip_bfloat16* adjh = (__hip_bfloat16*)((char*)d_ws + 65536 + (4 << 20)); // 268 MB

    k_degcast<<<dim3(NB * NN / 4),  dim3(256), 0, stream>>>(adj, norm, adjh);
    k_support<<<dim3(NB * NN / 16), dim3(256), 0, stream>>>(x, W, norm, snT);
    k_gemm10 <<<dim3(NN / BM, NB),  dim3(512), 0, stream>>>(adjh, snT, norm, bias, out);
}